// Round 7
// baseline (385.693 us; speedup 1.0000x reference)
//
#include <hip/hip_runtime.h>
#include <hip/hip_bf16.h>

#define N_ROWS 8192
#define DIM    128
#define TWO_N  16384
#define NBLK   64                         // 256-row/col block stripes
#define NTRI   (NBLK * (NBLK + 1) / 2)    // 2080 triangular blocks
#define EXP_TWO 7.38905609893065f
// sqrt(2 * log2(e)): folding exp(2*dot) == exp2(SCALE^2 * dot) into the operands
#define H_SCALE 1.6986436f

typedef __attribute__((ext_vector_type(8))) short short8;
typedef __attribute__((ext_vector_type(4))) float float4v;

__device__ inline float fast_exp2(float x) {
#if __has_builtin(__builtin_amdgcn_exp2f)
  return __builtin_amdgcn_exp2f(x);
#else
  return exp2f(x);
#endif
}

// ---------------------------------------------------------------------------
// Blocked H layout (MFMA-fragment-tiled):
//   element (row, k) -> tile T=row>>4, Kt=k>>5 ; chunk (row&15)*4 + ((k&31)>>3)
//   short addr = ((T*4 + Kt)*64 + (row&15)*4 + ((k&31)>>3))*8 + (k&7)
// A wave's MFMA fragment (lane = q*16+m reads row base+m, k Kt*32+q*8..+7)
// is then chunk m*4+q of ONE 1KB tile -> a single coalesced 1KB wave-load.
// ---------------------------------------------------------------------------

// ---------------------------------------------------------------------------
// Kernel 1: L2-normalize rows of h1,h2 (fp32), write bf16 H in the blocked
// layout, scaled by sqrt(2*log2 e) so the GEMM accumulator is the exp2 arg.
// Writes exact fp32 pos-dot per row; zeroes rowsum and the completion counter.
// One wave per row; block = 4 waves.
// ---------------------------------------------------------------------------
__global__ __launch_bounds__(256) void norm_kernel(
    const float* __restrict__ h1, const float* __restrict__ h2,
    __hip_bfloat16* __restrict__ Hb, float* __restrict__ posdot,
    float* __restrict__ rowsum, int* __restrict__ counter) {
  if (threadIdx.x < 8) rowsum[blockIdx.x * 8 + threadIdx.x] = 0.0f;
  if (blockIdx.x == 0 && threadIdx.x == 0) *counter = 0;

  int lane = threadIdx.x & 63;
  int w    = threadIdx.x >> 6;
  int row  = blockIdx.x * 4 + w;                  // 0..8191

  const float2* p1 = (const float2*)(h1 + (size_t)row * DIM);
  const float2* p2 = (const float2*)(h2 + (size_t)row * DIM);
  float2 v1 = p1[lane];
  float2 v2 = p2[lane];

  float ss1 = v1.x * v1.x + v1.y * v1.y;
  float ss2 = v2.x * v2.x + v2.y * v2.y;
  #pragma unroll
  for (int s = 32; s; s >>= 1) {
    ss1 += __shfl_xor(ss1, s);
    ss2 += __shfl_xor(ss2, s);
  }
  float inv1 = 1.0f / fmaxf(sqrtf(ss1), 1e-12f);
  float inv2 = 1.0f / fmaxf(sqrtf(ss2), 1e-12f);

  float ax = v1.x * inv1, ay = v1.y * inv1;
  float bx = v2.x * inv2, by = v2.y * inv2;

  float pd = ax * bx + ay * by;       // exact fp32 posdot (unscaled)
  #pragma unroll
  for (int s = 32; s; s >>= 1) pd += __shfl_xor(pd, s);

  // Blocked-layout write: lane covers k = 2*lane, 2*lane+1.
  // Kt = lane>>4, q8 = (lane&15)>>2, short-in-chunk = 2*(lane&3).
  int Kt = lane >> 4, q8 = (lane & 15) >> 2, sic = (lane & 3) * 2;
  short* Hs = (short*)Hb;
  {
    int r1 = row;
    size_t off = ((size_t)((r1 >> 4) * 4 + Kt) * 64 + (r1 & 15) * 4 + q8) * 8 + sic;
    __hip_bfloat162 t;
    t.x = __float2bfloat16(ax * H_SCALE); t.y = __float2bfloat16(ay * H_SCALE);
    *(__hip_bfloat162*)(Hs + off) = t;
  }
  {
    int r2 = row + N_ROWS;
    size_t off = ((size_t)((r2 >> 4) * 4 + Kt) * 64 + (r2 & 15) * 4 + q8) * 8 + sic;
    __hip_bfloat162 t;
    t.x = __float2bfloat16(bx * H_SCALE); t.y = __float2bfloat16(by * H_SCALE);
    *(__hip_bfloat162*)(Hs + off) = t;
  }

  if (lane == 0) posdot[row] = pd;
}

// ---------------------------------------------------------------------------
// Kernel 2: row sums of exp2(H H^T), upper block-triangle only (symmetry).
// 512 threads = 8 waves; wave owns 32 rows (A pinned: 2x4 frags = 32 VGPR).
// NO LDS staging, NO in-loop barriers: each wave streams the 256-col B panel
// from L2 as coalesced 1KB fragment loads (blocked layout), register
// double-buffered (bX/bY) so subtile cs+1 flies under compute of cs.
// Waves are fully independent until the final colacc exchange.
// Off-diagonal blocks also reduce each exp tile along the column axis into
// per-wave LDS slices (symmetric half), flushed once at the end.
// The LAST block to finish (device-scope counter) runs finalize inline.
// ---------------------------------------------------------------------------
__global__ __launch_bounds__(512, 2) void ntx_main(
    const __hip_bfloat16* __restrict__ Hb, float* __restrict__ rowsum,
    const float* __restrict__ posdot, int* __restrict__ counter,
    float* __restrict__ out) {
  __shared__ float colacc[8][256];    // 8 KB: per-wave col-sum slices
  __shared__ float red[16];
  __shared__ int is_last;
  const short* H = (const short*)Hb;

  int tid  = threadIdx.x;
  int lane = tid & 63;
  int w    = tid >> 6;      // 0..7
  int q    = lane >> 4;     // k-chunk selector within fragment
  int m    = lane & 15;     // row-within-subtile / col-within-subtile

  // Triangular decode: blockIdx.x -> (I, J) with J >= I over NBLK stripes.
  int t0 = blockIdx.x;
  int I = (int)((129.0f - sqrtf(129.0f * 129.0f - 8.0f * (float)t0)) * 0.5f);
  while ((I + 1) * (129 - (I + 1)) / 2 <= t0) ++I;   // fixup fp rounding
  while (I * (129 - I) / 2 > t0) --I;
  int J = I + (t0 - I * (129 - I) / 2);
  bool diag = (I == J);

  int rowbase = I * 256 + w * 32;
  int laneoff = (m * 4 + q) * 8;      // chunk offset within a 1KB tile, shorts

  // A fragments: 2 row-subtiles x 4 k-steps, blocked-layout loads, pinned.
  short8 a[2][4];
  #pragma unroll
  for (int r = 0; r < 2; ++r)
    #pragma unroll
    for (int s = 0; s < 4; ++s)
      a[r][s] = *(const short8*)(H + ((size_t)((I * 16 + w * 2 + r) * 4 + s) * 64) * 8 + laneoff);
  #pragma unroll
  for (int r = 0; r < 2; ++r)
    #pragma unroll
    for (int s = 0; s < 4; ++s)
      asm volatile("" : "+v"(a[r][s]));

  float rowacc[2][4];
  #pragma unroll
  for (int r = 0; r < 2; ++r)
    #pragma unroll
    for (int i = 0; i < 4; ++i) rowacc[r][i] = 0.0f;

  // B panel pointer: subtile cs, k-step s lives at J*32768 + cs*2048 + s*512.
  const short* gp = H + (size_t)J * 32768 + laneoff;

#define LOADB(bb, p) do {                         \
    bb[0] = *(const short8*)((p));                \
    bb[1] = *(const short8*)((p) + 512);          \
    bb[2] = *(const short8*)((p) + 1024);         \
    bb[3] = *(const short8*)((p) + 1536);         \
  } while (0)

#define COMPUTE(bb, cs_) do {                                              \
    float cp = 0.0f;                                                       \
    _Pragma("unroll")                                                      \
    for (int r = 0; r < 2; ++r) {                                          \
      float4v acc = {0.f, 0.f, 0.f, 0.f};                                  \
      _Pragma("unroll")                                                    \
      for (int s = 0; s < 4; ++s)                                          \
        acc = __builtin_amdgcn_mfma_f32_16x16x32_bf16(a[r][s], bb[s], acc, 0, 0, 0); \
      _Pragma("unroll")                                                    \
      for (int i = 0; i < 4; ++i) {                                        \
        float e = fast_exp2(acc[i]);   /* acc already = 2*log2e*dot */     \
        rowacc[r][i] += e;                                                 \
        cp += e;                                                           \
      }                                                                    \
    }                                                                      \
    if (!diag) {                                                           \
      cp += __shfl_xor(cp, 16);                                           \
      cp += __shfl_xor(cp, 32);                                           \
      if (q == 0) colacc[w][(cs_) * 16 + m] = cp;                          \
    }                                                                      \
  } while (0)

  short8 bX[4], bY[4];
  LOADB(bX, gp);
  #pragma unroll
  for (int cs = 0; cs < 16; cs += 2) {
    LOADB(bY, gp + 2048);              // subtile cs+1 in flight under COMPUTE
    COMPUTE(bX, cs);
    gp += 4096;
    if (cs + 2 < 16) LOADB(bX, gp);    // subtile cs+2 in flight
    COMPUTE(bY, cs + 1);
  }
#undef LOADB
#undef COMPUTE

  // Row sums: reduce across the 16 column-lanes holding the same rows.
  #pragma unroll
  for (int r = 0; r < 2; ++r)
    #pragma unroll
    for (int i = 0; i < 4; ++i) {
      float v = rowacc[r][i];
      v += __shfl_xor(v, 1);
      v += __shfl_xor(v, 2);
      v += __shfl_xor(v, 4);
      v += __shfl_xor(v, 8);
      rowacc[r][i] = v;
    }
  if (m == 0) {
    #pragma unroll
    for (int r = 0; r < 2; ++r)
      #pragma unroll
      for (int i = 0; i < 4; ++i)
        atomicAdd(&rowsum[rowbase + r * 16 + q * 4 + i], rowacc[r][i]);
  }

  // Col sums -> stripe J (symmetric contribution).
  if (!diag) {
    __syncthreads();
    if (tid < 256) {
      float v = 0.0f;
      #pragma unroll
      for (int ww = 0; ww < 8; ++ww) v += colacc[ww][tid];
      atomicAdd(&rowsum[J * 256 + tid], v);
    }
  }

  // ---- fused finalize: last block computes the loss ----
  __threadfence();          // order this thread's rowsum atomics
  __syncthreads();
  if (tid == 0) {
    int old = atomicAdd(counter, 1);
    is_last = (old == NTRI - 1) ? 1 : 0;
  }
  __syncthreads();
  if (is_last) {
    float ld = 0.0f, pp = 0.0f;
    for (int i = tid; i < TWO_N; i += 512) {
      float v = atomicAdd(&rowsum[i], 0.0f);   // device-scope read, XCD-safe
      ld += logf(v - EXP_TWO);
    }
    for (int i = tid; i < N_ROWS; i += 512) pp += posdot[i];
    #pragma unroll
    for (int s = 32; s; s >>= 1) {
      ld += __shfl_xor(ld, s);
      pp += __shfl_xor(pp, s);
    }
    if (lane == 0) { red[w] = ld; red[8 + w] = pp; }
    __syncthreads();
    if (tid == 0) {
      float tl = 0.0f, tp = 0.0f;
      #pragma unroll
      for (int i = 0; i < 8; ++i) { tl += red[i]; tp += red[8 + i]; }
      *out = (tl - 4.0f * tp) / (float)TWO_N;
    }
  }
}

extern "C" void kernel_launch(void* const* d_in, const int* in_sizes, int n_in,
                              void* d_out, int out_size, void* d_ws, size_t ws_size,
                              hipStream_t stream) {
  const float* h1 = (const float*)d_in[0];
  const float* h2 = (const float*)d_in[1];
  char* ws = (char*)d_ws;

  __hip_bfloat16* Hb = (__hip_bfloat16*)ws;                       // 4 MB (blocked)
  float* rowsum      = (float*)(ws + 4194304);                    // 64 KB
  float* posdot      = (float*)(ws + 4194304 + 65536);            // 32 KB
  int*   counter     = (int*)(ws + 4194304 + 65536 + 32768);      // 4 B
  float* out         = (float*)d_out;

  norm_kernel<<<N_ROWS / 4, 256, 0, stream>>>(h1, h2, Hb, posdot, rowsum, counter);
  ntx_main<<<NTRI, 512, 0, stream>>>(Hb, rowsum, posdot, counter, out);
}

// Round 8
// 160.527 us; speedup vs baseline: 2.4027x; 2.4027x over previous
//
#include <hip/hip_runtime.h>
#include <hip/hip_bf16.h>

#define N_ROWS 8192
#define DIM    128
#define TWO_N  16384
#define NBLK   64                         // 256-row/col block stripes
#define NTRI   (NBLK * (NBLK + 1) / 2)    // 2080 triangular blocks
#define EXP_TWO 7.38905609893065f
// sqrt(2 * log2(e)): folding exp(2*dot) == exp2(SCALE^2 * dot) into the operands
#define H_SCALE 1.6986436f

typedef __attribute__((ext_vector_type(8))) short short8;
typedef __attribute__((ext_vector_type(4))) float float4v;

__device__ inline float fast_exp2(float x) {
#if __has_builtin(__builtin_amdgcn_exp2f)
  return __builtin_amdgcn_exp2f(x);
#else
  return exp2f(x);
#endif
}

// ---------------------------------------------------------------------------
// Blocked H layout (MFMA-fragment-tiled):
//   element (row, k) -> tile T=row>>4, Kt=k>>5 ; chunk (row&15)*4 + ((k&31)>>3)
//   short addr = ((T*4 + Kt)*64 + (row&15)*4 + ((k&31)>>3))*8 + (k&7)
// A wave's MFMA fragment (lane = q*16+m reads row base+m, k Kt*32+q*8..+7)
// is then chunk m*4+q of ONE 1KB tile -> a single coalesced 1KB wave-load.
// ---------------------------------------------------------------------------

// ---------------------------------------------------------------------------
// Kernel 1: L2-normalize rows of h1,h2 (fp32), write bf16 H in the blocked
// layout, scaled by sqrt(2*log2 e) so the GEMM accumulator is the exp2 arg.
// Writes exact fp32 pos-dot per row; zeroes rowsum.
// One wave per row; block = 4 waves.
// ---------------------------------------------------------------------------
__global__ __launch_bounds__(256) void norm_kernel(
    const float* __restrict__ h1, const float* __restrict__ h2,
    __hip_bfloat16* __restrict__ Hb, float* __restrict__ posdot,
    float* __restrict__ rowsum) {
  if (threadIdx.x < 8) rowsum[blockIdx.x * 8 + threadIdx.x] = 0.0f;

  int lane = threadIdx.x & 63;
  int w    = threadIdx.x >> 6;
  int row  = blockIdx.x * 4 + w;                  // 0..8191

  const float2* p1 = (const float2*)(h1 + (size_t)row * DIM);
  const float2* p2 = (const float2*)(h2 + (size_t)row * DIM);
  float2 v1 = p1[lane];
  float2 v2 = p2[lane];

  float ss1 = v1.x * v1.x + v1.y * v1.y;
  float ss2 = v2.x * v2.x + v2.y * v2.y;
  #pragma unroll
  for (int s = 32; s; s >>= 1) {
    ss1 += __shfl_xor(ss1, s);
    ss2 += __shfl_xor(ss2, s);
  }
  float inv1 = 1.0f / fmaxf(sqrtf(ss1), 1e-12f);
  float inv2 = 1.0f / fmaxf(sqrtf(ss2), 1e-12f);

  float ax = v1.x * inv1, ay = v1.y * inv1;
  float bx = v2.x * inv2, by = v2.y * inv2;

  float pd = ax * bx + ay * by;       // exact fp32 posdot (unscaled)
  #pragma unroll
  for (int s = 32; s; s >>= 1) pd += __shfl_xor(pd, s);

  // Blocked-layout write: lane covers k = 2*lane, 2*lane+1.
  // Kt = lane>>4, q8 = (lane&15)>>2, short-in-chunk = 2*(lane&3).
  int Kt = lane >> 4, q8 = (lane & 15) >> 2, sic = (lane & 3) * 2;
  short* Hs = (short*)Hb;
  {
    int r1 = row;
    size_t off = ((size_t)((r1 >> 4) * 4 + Kt) * 64 + (r1 & 15) * 4 + q8) * 8 + sic;
    __hip_bfloat162 t;
    t.x = __float2bfloat16(ax * H_SCALE); t.y = __float2bfloat16(ay * H_SCALE);
    *(__hip_bfloat162*)(Hs + off) = t;
  }
  {
    int r2 = row + N_ROWS;
    size_t off = ((size_t)((r2 >> 4) * 4 + Kt) * 64 + (r2 & 15) * 4 + q8) * 8 + sic;
    __hip_bfloat162 t;
    t.x = __float2bfloat16(bx * H_SCALE); t.y = __float2bfloat16(by * H_SCALE);
    *(__hip_bfloat162*)(Hs + off) = t;
  }

  if (lane == 0) posdot[row] = pd;
}

// ---------------------------------------------------------------------------
// Kernel 2: row sums of exp2(H H^T), upper block-triangle only (symmetry).
// 512 threads = 8 waves; wave owns 32 rows (A pinned: 2x4 frags = 32 VGPR).
// NO LDS staging, NO in-loop barriers: each wave streams the 256-col B panel
// from L2 as coalesced 1KB fragment loads (blocked layout), register
// double-buffered (bX/bY) so subtile cs+1 flies under compute of cs.
// Off-diagonal blocks also reduce each exp tile along the column axis into
// per-wave LDS slices (symmetric half), flushed once at the end.
// NOTE (R5-R7 lesson): NO device-scope fence / fused finalize here — each
// block's __threadfence() forced an XCD-wide L2 writeback+invalidate,
// destroying H's L2 residency for concurrent blocks (330-343 us, all pipes
// idle). Finalize is a separate kernel again.
// ---------------------------------------------------------------------------
__global__ __launch_bounds__(512, 2) void ntx_main(
    const __hip_bfloat16* __restrict__ Hb, float* __restrict__ rowsum) {
  __shared__ float colacc[8][256];    // 8 KB: per-wave col-sum slices
  const short* H = (const short*)Hb;

  int tid  = threadIdx.x;
  int lane = tid & 63;
  int w    = tid >> 6;      // 0..7
  int q    = lane >> 4;     // k-chunk selector within fragment
  int m    = lane & 15;     // row-within-subtile / col-within-subtile

  // Triangular decode: blockIdx.x -> (I, J) with J >= I over NBLK stripes.
  int t0 = blockIdx.x;
  int I = (int)((129.0f - sqrtf(129.0f * 129.0f - 8.0f * (float)t0)) * 0.5f);
  while ((I + 1) * (129 - (I + 1)) / 2 <= t0) ++I;   // fixup fp rounding
  while (I * (129 - I) / 2 > t0) --I;
  int J = I + (t0 - I * (129 - I) / 2);
  bool diag = (I == J);

  int rowbase = I * 256 + w * 32;
  int laneoff = (m * 4 + q) * 8;      // chunk offset within a 1KB tile, shorts

  // A fragments: 2 row-subtiles x 4 k-steps, blocked-layout loads, pinned.
  short8 a[2][4];
  #pragma unroll
  for (int r = 0; r < 2; ++r)
    #pragma unroll
    for (int s = 0; s < 4; ++s)
      a[r][s] = *(const short8*)(H + ((size_t)((I * 16 + w * 2 + r) * 4 + s) * 64) * 8 + laneoff);
  #pragma unroll
  for (int r = 0; r < 2; ++r)
    #pragma unroll
    for (int s = 0; s < 4; ++s)
      asm volatile("" : "+v"(a[r][s]));

  float rowacc[2][4];
  #pragma unroll
  for (int r = 0; r < 2; ++r)
    #pragma unroll
    for (int i = 0; i < 4; ++i) rowacc[r][i] = 0.0f;

  // B panel pointer: subtile cs, k-step s lives at J*32768 + cs*2048 + s*512.
  const short* gp = H + (size_t)J * 32768 + laneoff;

#define LOADB(bb, p) do {                         \
    bb[0] = *(const short8*)((p));                \
    bb[1] = *(const short8*)((p) + 512);          \
    bb[2] = *(const short8*)((p) + 1024);         \
    bb[3] = *(const short8*)((p) + 1536);         \
  } while (0)

#define COMPUTE(bb, cs_) do {                                              \
    float cp = 0.0f;                                                       \
    _Pragma("unroll")                                                      \
    for (int r = 0; r < 2; ++r) {                                          \
      float4v acc = {0.f, 0.f, 0.f, 0.f};                                  \
      _Pragma("unroll")                                                    \
      for (int s = 0; s < 4; ++s)                                          \
        acc = __builtin_amdgcn_mfma_f32_16x16x32_bf16(a[r][s], bb[s], acc, 0, 0, 0); \
      _Pragma("unroll")                                                    \
      for (int i = 0; i < 4; ++i) {                                        \
        float e = fast_exp2(acc[i]);   /* acc already = 2*log2e*dot */     \
        rowacc[r][i] += e;                                                 \
        cp += e;                                                           \
      }                                                                    \
    }                                                                      \
    if (!diag) {                                                           \
      cp += __shfl_xor(cp, 16);                                           \
      cp += __shfl_xor(cp, 32);                                           \
      if (q == 0) colacc[w][(cs_) * 16 + m] = cp;                          \
    }                                                                      \
  } while (0)

  short8 bX[4], bY[4];
  LOADB(bX, gp);
  #pragma unroll
  for (int cs = 0; cs < 16; cs += 2) {
    LOADB(bY, gp + 2048);              // subtile cs+1 in flight under COMPUTE
    COMPUTE(bX, cs);
    gp += 4096;
    if (cs + 2 < 16) LOADB(bX, gp);    // subtile cs+2 in flight
    COMPUTE(bY, cs + 1);
  }
#undef LOADB
#undef COMPUTE

  // Row sums: reduce across the 16 column-lanes holding the same rows.
  #pragma unroll
  for (int r = 0; r < 2; ++r)
    #pragma unroll
    for (int i = 0; i < 4; ++i) {
      float v = rowacc[r][i];
      v += __shfl_xor(v, 1);
      v += __shfl_xor(v, 2);
      v += __shfl_xor(v, 4);
      v += __shfl_xor(v, 8);
      rowacc[r][i] = v;
    }
  if (m == 0) {
    #pragma unroll
    for (int r = 0; r < 2; ++r)
      #pragma unroll
      for (int i = 0; i < 4; ++i)
        atomicAdd(&rowsum[rowbase + r * 16 + q * 4 + i], rowacc[r][i]);
  }

  // Col sums -> stripe J (symmetric contribution).
  if (!diag) {
    __syncthreads();
    if (tid < 256) {
      float v = 0.0f;
      #pragma unroll
      for (int ww = 0; ww < 8; ++ww) v += colacc[ww][tid];
      atomicAdd(&rowsum[J * 256 + tid], v);
    }
  }
}

// ---------------------------------------------------------------------------
// Kernel 3: loss = ( sum_i log(rowsum_i - e^2) - 4 * sum_i posdot_i ) / 2N
// float4 loads + 4 independent logf per iter to break the dependent chain.
// ---------------------------------------------------------------------------
__global__ __launch_bounds__(1024) void finalize(
    const float* __restrict__ rowsum, const float* __restrict__ posdot,
    float* __restrict__ out) {
  __shared__ float red[32];
  int tid = threadIdx.x;
  const float4* rs4 = (const float4*)rowsum;
  const float4* pd4 = (const float4*)posdot;
  float ld = 0.0f, pp = 0.0f;
  #pragma unroll
  for (int it = 0; it < 4; ++it) {
    float4 v = rs4[tid + it * 1024];
    ld += logf(v.x - EXP_TWO) + logf(v.y - EXP_TWO) +
          logf(v.z - EXP_TWO) + logf(v.w - EXP_TWO);
  }
  #pragma unroll
  for (int it = 0; it < 2; ++it) {
    float4 v = pd4[tid + it * 1024];
    pp += v.x + v.y + v.z + v.w;
  }
  #pragma unroll
  for (int s = 32; s; s >>= 1) {
    ld += __shfl_xor(ld, s);
    pp += __shfl_xor(pp, s);
  }
  if ((tid & 63) == 0) {
    red[tid >> 6] = ld;
    red[16 + (tid >> 6)] = pp;
  }
  __syncthreads();
  if (tid == 0) {
    float tl = 0.0f, tp = 0.0f;
    #pragma unroll
    for (int i = 0; i < 16; ++i) { tl += red[i]; tp += red[16 + i]; }
    *out = (tl - 4.0f * tp) / (float)TWO_N;
  }
}

extern "C" void kernel_launch(void* const* d_in, const int* in_sizes, int n_in,
                              void* d_out, int out_size, void* d_ws, size_t ws_size,
                              hipStream_t stream) {
  const float* h1 = (const float*)d_in[0];
  const float* h2 = (const float*)d_in[1];
  char* ws = (char*)d_ws;

  __hip_bfloat16* Hb = (__hip_bfloat16*)ws;                       // 4 MB (blocked)
  float* rowsum      = (float*)(ws + 4194304);                    // 64 KB
  float* posdot      = (float*)(ws + 4194304 + 65536);            // 32 KB
  float* out         = (float*)d_out;

  norm_kernel<<<N_ROWS / 4, 256, 0, stream>>>(h1, h2, Hb, posdot, rowsum);
  ntx_main<<<NTRI, 512, 0, stream>>>(Hb, rowsum);
  finalize<<<1, 1024, 0, stream>>>(rowsum, posdot, out);
}

// Round 9
// 116.405 us; speedup vs baseline: 3.3134x; 1.3790x over previous
//
#include <hip/hip_runtime.h>
#include <hip/hip_bf16.h>

#define N_ROWS 8192
#define DIM    128
#define TWO_N  16384
#define NBLK   64                         // 256-row/col block stripes
#define NTRI   (NBLK * (NBLK + 1) / 2)    // 2080 triangular blocks
#define EXP_TWO 7.38905609893065f
// sqrt(2 * log2(e)): folding exp(2*dot) == exp2(SCALE^2 * dot) into the operands
#define H_SCALE 1.6986436f

typedef __attribute__((ext_vector_type(8))) short short8;
typedef __attribute__((ext_vector_type(4))) float float4v;

__device__ inline void async_copy16(const void* g, void* l) {
  __builtin_amdgcn_global_load_lds(
      (const __attribute__((address_space(1))) void*)g,
      (__attribute__((address_space(3))) void*)l, 16, 0, 0);
}

__device__ inline float fast_exp2(float x) {
#if __has_builtin(__builtin_amdgcn_exp2f)
  return __builtin_amdgcn_exp2f(x);
#else
  return exp2f(x);
#endif
}

// ---------------------------------------------------------------------------
// Blocked H layout, lane-sequential chunk order:
//   element (row,k) -> tile T=row>>4, Kt=k>>5 ;
//   chunk-in-tile = ((k&31)>>3)*16 + (row&15)   (== MFMA lane q*16+m)
//   short addr = (T*4 + Kt)*512 + chunk*8 + (k&7)
// A wave's MFMA fragment is chunk `lane` of ONE contiguous 1KB tile:
//  - global load: coalesced 1KB wave-read
//  - LDS read after a linear copy: lane-sequential ds_read_b128, conflict-free
// ---------------------------------------------------------------------------

// ---------------------------------------------------------------------------
// Kernel 1: L2-normalize rows of h1,h2 (fp32), write bf16 H in the blocked
// layout, scaled by sqrt(2*log2 e) so the GEMM accumulator is the exp2 arg.
// Writes exact fp32 pos-dot per row; zeroes rowsum. One wave per row.
// ---------------------------------------------------------------------------
__global__ __launch_bounds__(256) void norm_kernel(
    const float* __restrict__ h1, const float* __restrict__ h2,
    __hip_bfloat16* __restrict__ Hb, float* __restrict__ posdot,
    float* __restrict__ rowsum) {
  if (threadIdx.x < 8) rowsum[blockIdx.x * 8 + threadIdx.x] = 0.0f;

  int lane = threadIdx.x & 63;
  int w    = threadIdx.x >> 6;
  int row  = blockIdx.x * 4 + w;                  // 0..8191

  const float2* p1 = (const float2*)(h1 + (size_t)row * DIM);
  const float2* p2 = (const float2*)(h2 + (size_t)row * DIM);
  float2 v1 = p1[lane];
  float2 v2 = p2[lane];

  float ss1 = v1.x * v1.x + v1.y * v1.y;
  float ss2 = v2.x * v2.x + v2.y * v2.y;
  #pragma unroll
  for (int s = 32; s; s >>= 1) {
    ss1 += __shfl_xor(ss1, s);
    ss2 += __shfl_xor(ss2, s);
  }
  float inv1 = 1.0f / fmaxf(sqrtf(ss1), 1e-12f);
  float inv2 = 1.0f / fmaxf(sqrtf(ss2), 1e-12f);

  float ax = v1.x * inv1, ay = v1.y * inv1;
  float bx = v2.x * inv2, by = v2.y * inv2;

  float pd = ax * bx + ay * by;       // exact fp32 posdot (unscaled)
  #pragma unroll
  for (int s = 32; s; s >>= 1) pd += __shfl_xor(pd, s);

  // Blocked-layout write: lane covers k = 2*lane, 2*lane+1 (same chunk).
  // Kt = lane>>4, q = (lane&15)>>2, chunk = q*16 + (row&15), sic = 2*(lane&3).
  int Kt = lane >> 4, q8 = (lane & 15) >> 2, sic = (lane & 3) * 2;
  short* Hs = (short*)Hb;
  {
    int r1 = row;
    size_t off = (size_t)((r1 >> 4) * 4 + Kt) * 512 + (q8 * 16 + (r1 & 15)) * 8 + sic;
    __hip_bfloat162 t;
    t.x = __float2bfloat16(ax * H_SCALE); t.y = __float2bfloat16(ay * H_SCALE);
    *(__hip_bfloat162*)(Hs + off) = t;
  }
  {
    int r2 = row + N_ROWS;
    size_t off = (size_t)((r2 >> 4) * 4 + Kt) * 512 + (q8 * 16 + (r2 & 15)) * 8 + sic;
    __hip_bfloat162 t;
    t.x = __float2bfloat16(bx * H_SCALE); t.y = __float2bfloat16(by * H_SCALE);
    *(__hip_bfloat162*)(Hs + off) = t;
  }

  if (lane == 0) posdot[row] = pd;
}

// ---------------------------------------------------------------------------
// Kernel 2: row sums of exp2(H H^T), upper block-triangle only (symmetry).
// 512 threads = 8 waves; wave owns 32 rows (A pinned: 2x4 frags = 32 VGPR).
// The ENTIRE 256-col B panel (64 KB, contiguous in blocked layout) is staged
// into LDS once via 8 linear global_load_lds per thread; ONE barrier; then
// the whole compute phase is barrier-free and global-load-free:
// 16 subtiles x (4 conflict-free ds_read_b128 + 8 MFMA + 8 exp2).
// LDS = 64KB panel + 8KB colacc -> 2 blocks/CU; one block's staging overlaps
// the other's compute (TLP), so no in-loop pipeline machinery is needed.
// NOTE (R5-R7 lesson): NO device-scope fence / fused finalize here — a
// per-block __threadfence forced XCD-wide L2 writeback+invalidate (3-5x).
// ---------------------------------------------------------------------------
__global__ __launch_bounds__(512, 2) void ntx_main(
    const __hip_bfloat16* __restrict__ Hb, float* __restrict__ rowsum) {
  __shared__ short smem[32768];       // 64 KB: full B panel, blocked order
  __shared__ float colacc[8][256];    // 8 KB: per-wave col-sum slices
  const short* H = (const short*)Hb;

  int tid  = threadIdx.x;
  int lane = tid & 63;
  int w    = tid >> 6;      // 0..7
  int q    = lane >> 4;     // k-chunk selector within fragment
  int m    = lane & 15;     // row-within-subtile / col-within-subtile

  // Triangular decode: blockIdx.x -> (I, J) with J >= I over NBLK stripes.
  int t0 = blockIdx.x;
  int I = (int)((129.0f - sqrtf(129.0f * 129.0f - 8.0f * (float)t0)) * 0.5f);
  while ((I + 1) * (129 - (I + 1)) / 2 <= t0) ++I;   // fixup fp rounding
  while (I * (129 - I) / 2 > t0) --I;
  int J = I + (t0 - I * (129 - I) / 2);
  bool diag = (I == J);

  int rowbase = I * 256 + w * 32;

  // Stage the full B panel (stripe J, 64 KB contiguous) into LDS, linearly.
  const short* gpanel = H + (size_t)J * 32768;
  #pragma unroll
  for (int it = 0; it < 8; ++it)
    async_copy16(gpanel + it * 4096 + tid * 8, (void*)&smem[it * 4096 + tid * 8]);

  // A fragments: 2 row-subtiles x 4 k-steps, blocked-layout loads, pinned.
  short8 a[2][4];
  #pragma unroll
  for (int r = 0; r < 2; ++r)
    #pragma unroll
    for (int s = 0; s < 4; ++s)
      a[r][s] = *(const short8*)(H + (size_t)((I * 16 + w * 2 + r) * 4 + s) * 512 + lane * 8);
  #pragma unroll
  for (int r = 0; r < 2; ++r)
    #pragma unroll
    for (int s = 0; s < 4; ++s)
      asm volatile("" : "+v"(a[r][s]));

  float rowacc[2][4];
  #pragma unroll
  for (int r = 0; r < 2; ++r)
    #pragma unroll
    for (int i = 0; i < 4; ++i) rowacc[r][i] = 0.0f;

  __syncthreads();   // single staging barrier (drains vmcnt for the panel)

  // Barrier-free compute: 16 subtiles from LDS.
  #pragma unroll 4
  for (int cs = 0; cs < 16; ++cs) {
    short8 b[4];
    #pragma unroll
    for (int s = 0; s < 4; ++s)
      b[s] = *(const short8*)&smem[cs * 2048 + s * 512 + lane * 8];
    float cp = 0.0f;
    #pragma unroll
    for (int r = 0; r < 2; ++r) {
      float4v acc = {0.f, 0.f, 0.f, 0.f};
      #pragma unroll
      for (int s = 0; s < 4; ++s)
        acc = __builtin_amdgcn_mfma_f32_16x16x32_bf16(a[r][s], b[s], acc, 0, 0, 0);
      #pragma unroll
      for (int i = 0; i < 4; ++i) {
        float e = fast_exp2(acc[i]);   // acc already = 2*log2e*dot
        rowacc[r][i] += e;
        cp += e;
      }
    }
    if (!diag) {
      // sum over the 4 q-groups -> col sum over this wave's 32 rows
      cp += __shfl_xor(cp, 16);
      cp += __shfl_xor(cp, 32);
      if (q == 0) colacc[w][cs * 16 + m] = cp;
    }
  }

  // Row sums: reduce across the 16 column-lanes holding the same rows.
  #pragma unroll
  for (int r = 0; r < 2; ++r)
    #pragma unroll
    for (int i = 0; i < 4; ++i) {
      float v = rowacc[r][i];
      v += __shfl_xor(v, 1);
      v += __shfl_xor(v, 2);
      v += __shfl_xor(v, 4);
      v += __shfl_xor(v, 8);
      rowacc[r][i] = v;
    }
  if (m == 0) {
    #pragma unroll
    for (int r = 0; r < 2; ++r)
      #pragma unroll
      for (int i = 0; i < 4; ++i)
        atomicAdd(&rowsum[rowbase + r * 16 + q * 4 + i], rowacc[r][i]);
  }

  // Col sums -> stripe J (symmetric contribution).
  if (!diag) {
    __syncthreads();
    if (tid < 256) {
      float v = 0.0f;
      #pragma unroll
      for (int ww = 0; ww < 8; ++ww) v += colacc[ww][tid];
      atomicAdd(&rowsum[J * 256 + tid], v);
    }
  }
}

// ---------------------------------------------------------------------------
// Kernel 3: loss = ( sum_i log(rowsum_i - e^2) - 4 * sum_i posdot_i ) / 2N
// float4 loads + 4 independent logf per iter to break the dependent chain.
// ---------------------------------------------------------------------------
__global__ __launch_bounds__(1024) void finalize(
    const float* __restrict__ rowsum, const float* __restrict__ posdot,
    float* __restrict__ out) {
  __shared__ float red[32];
  int tid = threadIdx.x;
  const float4* rs4 = (const float4*)rowsum;
  const float4* pd4 = (const float4*)posdot;
  float ld = 0.0f, pp = 0.0f;
  #pragma unroll
  for (int it = 0; it < 4; ++it) {
    float4 v = rs4[tid + it * 1024];
    ld += logf(v.x - EXP_TWO) + logf(v.y - EXP_TWO) +
          logf(v.z - EXP_TWO) + logf(v.w - EXP_TWO);
  }
  #pragma unroll
  for (int it = 0; it < 2; ++it) {
    float4 v = pd4[tid + it * 1024];
    pp += v.x + v.y + v.z + v.w;
  }
  #pragma unroll
  for (int s = 32; s; s >>= 1) {
    ld += __shfl_xor(ld, s);
    pp += __shfl_xor(pp, s);
  }
  if ((tid & 63) == 0) {
    red[tid >> 6] = ld;
    red[16 + (tid >> 6)] = pp;
  }
  __syncthreads();
  if (tid == 0) {
    float tl = 0.0f, tp = 0.0f;
    #pragma unroll
    for (int i = 0; i < 16; ++i) { tl += red[i]; tp += red[16 + i]; }
    *out = (tl - 4.0f * tp) / (float)TWO_N;
  }
}

extern "C" void kernel_launch(void* const* d_in, const int* in_sizes, int n_in,
                              void* d_out, int out_size, void* d_ws, size_t ws_size,
                              hipStream_t stream) {
  const float* h1 = (const float*)d_in[0];
  const float* h2 = (const float*)d_in[1];
  char* ws = (char*)d_ws;

  __hip_bfloat16* Hb = (__hip_bfloat16*)ws;                       // 4 MB (blocked)
  float* rowsum      = (float*)(ws + 4194304);                    // 64 KB
  float* posdot      = (float*)(ws + 4194304 + 65536);            // 32 KB
  float* out         = (float*)d_out;

  norm_kernel<<<N_ROWS / 4, 256, 0, stream>>>(h1, h2, Hb, posdot, rowsum);
  ntx_main<<<NTRI, 512, 0, stream>>>(Hb, rowsum);
  finalize<<<1, 1024, 0, stream>>>(rowsum, posdot, out);
}